// Round 3
// baseline (325.996 us; speedup 1.0000x reference)
//
#include <hip/hip_runtime.h>
#include <hip/hip_bf16.h>
#include <stdint.h>

// PixproLoss: out = -(sum_masked cos_sim / count_mask), B=2048, C=256, P=49.
// R6 = R3 structure (no LDS transpose: m lives in registers as MFMA A-operand,
// maskS = mask*inv_nm bf16 as B-operand; epilogue dots b against m2 in fp32)
// with the occupancy caps removed:
//   - __launch_bounds__(512, 8): 4 blocks/CU (32 waves) for phase mixing;
//     VGPR must stay <= 64 (so b-loads are NOT hoisted across the MFMA).
//   - distributed inv_nm (normredW[8][64] + per-thread 8-row sums) kills the
//     single-wave inv phase and one barrier (3 barriers total).
// R4/R5 lessons kept: every load burst is consumed before the next barrier;
// no cross-barrier register prefetch; no scalar bf16 transpose-stores.

typedef __attribute__((ext_vector_type(8))) short short8;
typedef __attribute__((ext_vector_type(4))) float floatx4;

#define P 49
#define CP 12544           // C*P
#define NMASK 2401         // P*P
#define MS_STRIDE 72       // maskS LDS row stride (bf16): 64 data + 8 pad

__device__ __forceinline__ short8 cvt8(float4 a, float4 b) {
  union { __hip_bfloat162 h2; short s2[2]; } t;
  short8 r;
  t.h2 = __float22bfloat162_rn(make_float2(a.x, a.y)); r[0] = t.s2[0]; r[1] = t.s2[1];
  t.h2 = __float22bfloat162_rn(make_float2(a.z, a.w)); r[2] = t.s2[0]; r[3] = t.s2[1];
  t.h2 = __float22bfloat162_rn(make_float2(b.x, b.y)); r[4] = t.s2[0]; r[5] = t.s2[1];
  t.h2 = __float22bfloat162_rn(make_float2(b.z, b.w)); r[6] = t.s2[0]; r[7] = t.s2[1];
  return r;
}

__global__ __launch_bounds__(512, 8) void pixpro_main(
    const float* __restrict__ base, const float* __restrict__ moment,
    const int* __restrict__ A, float* __restrict__ ws_num, float* __restrict__ ws_cnt)
{
  __shared__ __align__(16) uint16_t maskS[P * MS_STRIDE];      // mask*inv_nm bf16: 7.1 KB
  __shared__ __align__(16) float normredW[8 * 64];             // [wave][q] nm^2 partials: 2 KB
  __shared__ __align__(16) float SQred[8 * 4 * 16 * 2];        // [w][pt][mr][{S,Q}]: 4 KB
  __shared__ float cntred[8];

  const int b    = blockIdx.x;
  const int tid  = threadIdx.x;
  const int lane = tid & 63;
  const int wv   = tid >> 6;          // 0..7
  const int mrow = lane & 15;
  const int kgrp = (lane >> 4) & 3;

  const float* gb = base   + (size_t)b * CP;
  const float* gm = moment + (size_t)b * CP;
  const int*   gA = A      + (size_t)b * NMASK;

  // ---- P1: load m fragments fp32 from global (wave wv owns c-tiles 2wv, 2wv+1) ----
  // A-frag layout: lane -> A[m = mrow][k = kgrp*8 + j]; here m = c-within-tile, k = q.
  short8 afrag[2][2];                 // [cti][kt], bf16
  float s0[8], s1[8];                 // per-q nm^2 partials for q = kt*32 + kgrp*8 + j
  #pragma unroll
  for (int j = 0; j < 8; ++j) { s0[j] = 0.f; s1[j] = 0.f; }

  #pragma unroll
  for (int cti = 0; cti < 2; ++cti) {
    const int c = (2 * wv + cti) * 16 + mrow;
    const float* row = gm + c * P;
    float4 a0 = *(const float4*)(row + kgrp * 8);
    float4 a1 = *(const float4*)(row + kgrp * 8 + 4);
    float4 b0, b1;
    if (kgrp < 2) {
      b0 = *(const float4*)(row + 32 + kgrp * 8);
      b1 = *(const float4*)(row + 32 + kgrp * 8 + 4);
    } else if (kgrp == 2) {
      b0 = make_float4(row[48], 0.f, 0.f, 0.f);   // q=48 only; always in-bounds
      b1 = make_float4(0.f, 0.f, 0.f, 0.f);
    } else {
      b0 = make_float4(0.f, 0.f, 0.f, 0.f);
      b1 = make_float4(0.f, 0.f, 0.f, 0.f);
    }
    s0[0] = fmaf(a0.x, a0.x, s0[0]); s0[1] = fmaf(a0.y, a0.y, s0[1]);
    s0[2] = fmaf(a0.z, a0.z, s0[2]); s0[3] = fmaf(a0.w, a0.w, s0[3]);
    s0[4] = fmaf(a1.x, a1.x, s0[4]); s0[5] = fmaf(a1.y, a1.y, s0[5]);
    s0[6] = fmaf(a1.z, a1.z, s0[6]); s0[7] = fmaf(a1.w, a1.w, s0[7]);
    s1[0] = fmaf(b0.x, b0.x, s1[0]); s1[1] = fmaf(b0.y, b0.y, s1[1]);
    s1[2] = fmaf(b0.z, b0.z, s1[2]); s1[3] = fmaf(b0.w, b0.w, s1[3]);
    s1[4] = fmaf(b1.x, b1.x, s1[4]); s1[5] = fmaf(b1.y, b1.y, s1[5]);
    s1[6] = fmaf(b1.z, b1.z, s1[6]); s1[7] = fmaf(b1.w, b1.w, s1[7]);
    afrag[cti][0] = cvt8(a0, a1);
    afrag[cti][1] = cvt8(b0, b1);
  }

  // ---- mask loads for B-build (issued before barrier A; consumed after it) ----
  const bool btask = tid < P * 8;     // 392 tasks: p = tid>>3, q-group = tid&7
  const int  bp    = tid >> 3;
  const int  bqg   = tid & 7;
  const int  bq0   = bqg * 8;
  int bmask[8];
  #pragma unroll
  for (int j = 0; j < 8; ++j) bmask[j] = 0;
  if (btask) {
    const int* Ar = gA + bp * P + bq0;
    if (bqg <= 5) {                   // q <= 47, fully valid & in-bounds
      int4 u0 = *(const int4*)(Ar);
      int4 u1 = *(const int4*)(Ar + 4);
      bmask[0] = u0.x; bmask[1] = u0.y; bmask[2] = u0.z; bmask[3] = u0.w;
      bmask[4] = u1.x; bmask[5] = u1.y; bmask[6] = u1.z; bmask[7] = u1.w;
    } else if (bqg == 6) {            // only q=48 valid (scalar avoids OOB at p=48)
      bmask[0] = Ar[0];
    }                                 // bqg == 7: all padding zeros
  }

  // ---- full-wave norm reduce over mrow (xor 1,2,4,8); 4 holders/wave ----
  #pragma unroll
  for (int j = 0; j < 8; ++j) {
    s0[j] += __shfl_xor(s0[j], 1); s0[j] += __shfl_xor(s0[j], 2);
    s0[j] += __shfl_xor(s0[j], 4); s0[j] += __shfl_xor(s0[j], 8);
    s1[j] += __shfl_xor(s1[j], 1); s1[j] += __shfl_xor(s1[j], 2);
    s1[j] += __shfl_xor(s1[j], 4); s1[j] += __shfl_xor(s1[j], 8);
  }
  if (mrow == 0) {
    float* nb_ = &normredW[wv * 64 + kgrp * 8];
    *(float4*)(nb_ + 0)  = make_float4(s0[0], s0[1], s0[2], s0[3]);
    *(float4*)(nb_ + 4)  = make_float4(s0[4], s0[5], s0[6], s0[7]);
    *(float4*)(nb_ + 32) = make_float4(s1[0], s1[1], s1[2], s1[3]);
    *(float4*)(nb_ + 36) = make_float4(s1[4], s1[5], s1[6], s1[7]);
  }
  __syncthreads();   // barrier A

  // ---- B-build with distributed inv_nm: maskS[p][q] = mask ? inv_nm[q] : 0 ----
  int cntpart = 0;
  if (btask) {
    float4 a0 = make_float4(0.f, 0.f, 0.f, 0.f);
    float4 a1 = make_float4(0.f, 0.f, 0.f, 0.f);
    #pragma unroll
    for (int w = 0; w < 8; ++w) {
      const float* nr = &normredW[w * 64 + bq0];
      float4 u0 = *(const float4*)(nr);
      float4 u1 = *(const float4*)(nr + 4);
      a0.x += u0.x; a0.y += u0.y; a0.z += u0.z; a0.w += u0.w;
      a1.x += u1.x; a1.y += u1.y; a1.z += u1.z; a1.w += u1.w;
    }
    float4 f0, f1;
    f0.x = bmask[0] ? (1.0f / fmaxf(sqrtf(a0.x), 1e-6f)) : 0.f;
    f0.y = bmask[1] ? (1.0f / fmaxf(sqrtf(a0.y), 1e-6f)) : 0.f;
    f0.z = bmask[2] ? (1.0f / fmaxf(sqrtf(a0.z), 1e-6f)) : 0.f;
    f0.w = bmask[3] ? (1.0f / fmaxf(sqrtf(a0.w), 1e-6f)) : 0.f;
    f1.x = bmask[4] ? (1.0f / fmaxf(sqrtf(a1.x), 1e-6f)) : 0.f;
    f1.y = bmask[5] ? (1.0f / fmaxf(sqrtf(a1.y), 1e-6f)) : 0.f;
    f1.z = bmask[6] ? (1.0f / fmaxf(sqrtf(a1.z), 1e-6f)) : 0.f;
    f1.w = bmask[7] ? (1.0f / fmaxf(sqrtf(a1.w), 1e-6f)) : 0.f;
    #pragma unroll
    for (int j = 0; j < 8; ++j) cntpart += bmask[j];
    *(short8*)&maskS[bp * MS_STRIDE + bq0] = cvt8(f0, f1);
  }
  __syncthreads();   // barrier B

  // ---- MFMA: m2 tiles; B-frag: lane -> B[k = kgrp*8+j][n = mrow] ----
  const int pbase[4] = {0, 16, 32, 33};   // tile 3 = rows 33..48 (dedup in epilogue)
  floatx4 acc[2][4];
  #pragma unroll
  for (int i = 0; i < 2; ++i)
    #pragma unroll
    for (int j = 0; j < 4; ++j) acc[i][j] = (floatx4){0.f, 0.f, 0.f, 0.f};

  #pragma unroll
  for (int kt = 0; kt < 2; ++kt) {
    short8 bfr[4];
    #pragma unroll
    for (int pt = 0; pt < 4; ++pt)
      bfr[pt] = *(const short8*)&maskS[(pbase[pt] + mrow) * MS_STRIDE + kt * 32 + kgrp * 8];
    #pragma unroll
    for (int cti = 0; cti < 2; ++cti)
      #pragma unroll
      for (int pt = 0; pt < 4; ++pt)
        acc[cti][pt] = __builtin_amdgcn_mfma_f32_16x16x32_bf16(afrag[cti][kt], bfr[pt], acc[cti][pt], 0, 0, 0);
  }

  // ---- Epilogue: S[p] = sum_c b[c,p]*m2[c,p], Q[p] = sum_c b[c,p]^2 ----
  // Per-cti 16-load bursts, consumed immediately (keeps VGPR <= 64 for 8 waves/EU).
  // D layout: col = lane&15 -> p-within-tile; row = kgrp*4+r -> c-within-tile.
  float S[4] = {0.f, 0.f, 0.f, 0.f}, Qn[4] = {0.f, 0.f, 0.f, 0.f};
  #pragma unroll
  for (int cti = 0; cti < 2; ++cti) {
    float bv[4][4];
    #pragma unroll
    for (int pt = 0; pt < 4; ++pt) {
      const int pd = pbase[pt] + mrow;
      const bool pv = (pt < 3) || (mrow == 15);   // dedup rows 33..47 of tile 3
      #pragma unroll
      for (int r = 0; r < 4; ++r) {
        const int c = (2 * wv + cti) * 16 + kgrp * 4 + r;
        float v = gb[c * P + pd];
        bv[pt][r] = pv ? v : 0.f;
      }
    }
    #pragma unroll
    for (int pt = 0; pt < 4; ++pt)
      #pragma unroll
      for (int r = 0; r < 4; ++r) {
        S[pt]  = fmaf(bv[pt][r], acc[cti][pt][r], S[pt]);
        Qn[pt] = fmaf(bv[pt][r], bv[pt][r], Qn[pt]);
      }
  }

  // reduce over kgrp (lane bits 4,5)
  #pragma unroll
  for (int pt = 0; pt < 4; ++pt) {
    S[pt]  += __shfl_xor(S[pt], 16);  S[pt]  += __shfl_xor(S[pt], 32);
    Qn[pt] += __shfl_xor(Qn[pt], 16); Qn[pt] += __shfl_xor(Qn[pt], 32);
  }
  float cntf = (float)cntpart;
  #pragma unroll
  for (int off = 32; off > 0; off >>= 1) cntf += __shfl_xor(cntf, off);

  if (lane < 16) {
    #pragma unroll
    for (int pt = 0; pt < 4; ++pt)
      *(float2*)&SQred[((wv * 4 + pt) * 16 + mrow) * 2] = make_float2(S[pt], Qn[pt]);
  }
  if (lane == 0) cntred[wv] = cntf;
  __syncthreads();   // barrier C

  // ---- final: num = sum_p S[p]/max(||b_p||,eps); one wave ----
  if (tid < 64) {
    float num = 0.f, cc = 0.f;
    if (tid < P) {
      const int pt = tid >> 4;                       // 48 -> 3
      const int mr = (pt == 3) ? 15 : (tid & 15);
      float Sp = 0.f, Qp = 0.f;
      #pragma unroll
      for (int w = 0; w < 8; ++w) {
        const int idx = ((w * 4 + pt) * 16 + mr) * 2;
        Sp += SQred[idx];
        Qp += SQred[idx + 1];
      }
      num = Sp * (1.0f / fmaxf(sqrtf(Qp), 1e-6f));
    }
    if (tid < 8) cc = cntred[tid];
    #pragma unroll
    for (int off = 32; off > 0; off >>= 1) {
      num += __shfl_xor(num, off);
      cc  += __shfl_xor(cc, off);
    }
    if (tid == 0) { ws_num[b] = num; ws_cnt[b] = cc; }
  }
}

__global__ __launch_bounds__(256) void pixpro_reduce(
    const float* __restrict__ ws_num, const float* __restrict__ ws_cnt,
    float* __restrict__ out)
{
  __shared__ float rn[4], rc[4];
  float n = 0.f, c = 0.f;
  for (int i = threadIdx.x; i < 2048; i += 256) { n += ws_num[i]; c += ws_cnt[i]; }
  #pragma unroll
  for (int off = 32; off > 0; off >>= 1) {
    n += __shfl_down(n, off, 64);
    c += __shfl_down(c, off, 64);
  }
  const int wv = threadIdx.x >> 6, lane = threadIdx.x & 63;
  if (lane == 0) { rn[wv] = n; rc[wv] = c; }
  __syncthreads();
  if (threadIdx.x == 0) {
    float N = rn[0] + rn[1] + rn[2] + rn[3];
    float D = rc[0] + rc[1] + rc[2] + rc[3];
    out[0] = -(N / D);
  }
}

extern "C" void kernel_launch(void* const* d_in, const int* in_sizes, int n_in,
                              void* d_out, int out_size, void* d_ws, size_t ws_size,
                              hipStream_t stream) {
  const float* base   = (const float*)d_in[0];
  const float* moment = (const float*)d_in[1];
  const int*   A      = (const int*)d_in[2];
  float* ws_num = (float*)d_ws;          // 2048 floats
  float* ws_cnt = ws_num + 2048;         // 2048 floats
  pixpro_main<<<2048, 512, 0, stream>>>(base, moment, A, ws_num, ws_cnt);
  pixpro_reduce<<<1, 256, 0, stream>>>(ws_num, ws_cnt, (float*)d_out);
}